// Round 20
// baseline (140.899 us; speedup 1.0000x reference)
//
#include <hip/hip_runtime.h>

typedef __attribute__((ext_vector_type(8))) short bf16x8;
typedef __attribute__((ext_vector_type(4))) float f32x4;

#define HWSZ 65536
#define WSW_OFF 0
#define ZP_OFF  131072
#define XT_OFF  262144

#define VMCNT(n) do { asm volatile("s_waitcnt vmcnt(" #n ")" ::: "memory"); \
                      __builtin_amdgcn_sched_barrier(0); } while (0)
#define BARRIER() do { __builtin_amdgcn_s_barrier(); \
                       __builtin_amdgcn_sched_barrier(0); } while (0)

__device__ inline unsigned to_bf16u(float f) {
    union { float f; unsigned u; } c; c.f = f;
    unsigned u = c.u;
    return (u + 0x7fffu + ((u >> 16) & 1u)) >> 16;   // round-nearest-even
}

// Weights fp32 [co][ci][9] -> bf16 LINEAR wsw [chunk][kpos][co64][ci32]; zero zpage
__global__ void wcvt(const float* __restrict__ wgt, char* __restrict__ ws) {
    if (blockIdx.x == 0 && threadIdx.x < 64)
        ((unsigned*)(ws + ZP_OFF))[threadIdx.x] = 0;
    unsigned short* wsw = (unsigned short*)(ws + WSW_OFF);
    int idx = blockIdx.x * 256 + threadIdx.x;       // 36864 total
    int co   = idx / 576;
    int rem  = idx - co * 576;
    int ci   = rem / 9;
    int kpos = rem - ci * 9;
    unsigned short v = (unsigned short)to_bf16u(wgt[idx]);
    int chunk = ci >> 5, cil = ci & 31;
    wsw[((chunk * 9 + kpos) * 64 + co) * 32 + cil] = v;
}

// x fp32 NCHW -> bf16 channels-last xt[b][pix][octet-slot], column-swizzle baked in.
__global__ __launch_bounds__(256) void xcvt(const float* __restrict__ x, char* __restrict__ ws) {
    char* xt = ws + XT_OFF;
    const int tid = threadIdx.x;
    const int p4 = tid & 31, o = tid >> 5;
    const int pix0 = blockIdx.x * 128 + p4 * 4;
    const int b = blockIdx.y;
    const float* src = x + ((size_t)b * 64 + o * 8) * HWSZ + pix0;
    float4 v[8];
    #pragma unroll
    for (int k = 0; k < 8; ++k) v[k] = *(const float4*)(src + (size_t)k * HWSZ);
    #pragma unroll
    for (int j = 0; j < 4; ++j) {
        int pix = pix0 + j;
        int w = pix & 255;
        float e[8];
        e[0]=v[0].x; e[1]=v[1].x; e[2]=v[2].x; e[3]=v[3].x;
        e[4]=v[4].x; e[5]=v[5].x; e[6]=v[6].x; e[7]=v[7].x;
        if (j == 1) { e[0]=v[0].y; e[1]=v[1].y; e[2]=v[2].y; e[3]=v[3].y;
                      e[4]=v[4].y; e[5]=v[5].y; e[6]=v[6].y; e[7]=v[7].y; }
        if (j == 2) { e[0]=v[0].z; e[1]=v[1].z; e[2]=v[2].z; e[3]=v[3].z;
                      e[4]=v[4].z; e[5]=v[5].z; e[6]=v[6].z; e[7]=v[7].z; }
        if (j == 3) { e[0]=v[0].w; e[1]=v[1].w; e[2]=v[2].w; e[3]=v[3].w;
                      e[4]=v[4].w; e[5]=v[5].w; e[6]=v[6].w; e[7]=v[7].w; }
        unsigned u[4];
        #pragma unroll
        for (int k = 0; k < 4; ++k)
            u[k] = to_bf16u(e[2 * k]) | (to_bf16u(e[2 * k + 1]) << 16);
        int slot = o ^ (((w + 1) >> 1) & 3);   // XOR stays within o's chunk-half
        *(uint4*)(xt + (size_t)(b * HWSZ + pix) * 128 + slot * 16) = (uint4){u[0], u[1], u[2], u[3]};
    }
}

// Persistent conv: 256 blocks x 512 threads, counted-vmcnt pipeline, B in registers.
__global__ __launch_bounds__(512, 1) void maskconv_mfma(
    const char* __restrict__ ws, const int* __restrict__ mask,
    const float* __restrict__ bias, float* __restrict__ out)
{
    __shared__ unsigned short xs[2 * 384 * 32];   // 49152 B: chunk0 | chunk1 x-tiles

    const int tid  = threadIdx.x;
    const int lane = tid & 63;
    const int wv   = tid >> 6;          // wave 0..7
    const int coh  = wv >> 2;           // co-half
    const int rg   = wv & 3;            // row-group: rows rg*2..rg*2+1
    const int l15  = lane & 15;
    const int l4   = lane >> 4;
    const int pil  = lane >> 2;         // pixel-in-instruction 0..15
    const int slot = lane & 3;

    const int bk = blockIdx.x;          // 0..255
    char* xsb = (char*)xs;

    // ---- B (weights) in registers: both chunks, loaded once ----
    bf16x8 b0[18], b1[18];
    {
        const unsigned short* wbase = (const unsigned short*)(ws + WSW_OFF);
        #pragma unroll
        for (int k = 0; k < 9; ++k)
            #pragma unroll
            for (int j = 0; j < 2; ++j) {
                int co = coh * 32 + j * 16 + l15;
                b0[k * 2 + j] = *(const bf16x8*)(wbase + ((0 * 9 + k) * 64 + co) * 32 + l4 * 8);
                b1[k * 2 + j] = *(const bf16x8*)(wbase + ((1 * 9 + k) * 64 + co) * 32 + l4 * 8);
            }
    }

    // ---- stage x chunk for unit u: 3 glds/wave (incl. dummies), pure async ----
    auto stage_x = [&](int u, int chunk) {
        const int b  = u >> 8;
        const int tile = u & 255;
        const int tw = (tile & 7) * 32;
        const int th = (tile >> 3) * 8;
        #pragma unroll
        for (int q = 0; q < 3; ++q) {
            int i  = wv * 3 + q;        // 0..23
            int pi = i * 16 + pil;
            int r   = pi / 34;
            int lcv = pi - r * 34;
            int gr = th - 1 + r;
            int gc = tw - 1 + lcv;
            bool inb = (pi < 340) & ((unsigned)gr < 256u) & ((unsigned)gc < 256u);
            unsigned off = inb
                ? (unsigned)(XT_OFF + (unsigned)((b * HWSZ) + (gr << 8) + gc) * 128u + slot * 16)
                : (unsigned)(ZP_OFF + slot * 16);
            const char* g = ws + off + chunk * 64;
            unsigned short* l = xs + chunk * 12288 + i * 512;
            __builtin_amdgcn_global_load_lds(
                (const __attribute__((address_space(1))) void*)(const void*)g,
                (__attribute__((address_space(3))) void*)(void*)l, 16, 0, 0);
        }
    };

    f32x4 acc[4][2];

    auto do_mfma = [&](int chunk) {
        #pragma unroll
        for (int kh = 0; kh < 3; ++kh) {
            #pragma unroll
            for (int kw = 0; kw < 3; ++kw) {
                const int kpos = kh * 3 + kw;
                #pragma unroll
                for (int f = 0; f < 4; ++f) {
                    int fr = f >> 1, wh = f & 1;
                    int lc = wh * 16 + l15 + kw;
                    int r  = rg * 2 + fr + kh;
                    int s  = (lc >> 1) & 3;
                    bf16x8 afrag = *(const bf16x8*)(xsb + chunk * 24576 + (r * 34 + lc) * 64 + ((l4 ^ s) << 4));
                    #pragma unroll
                    for (int j = 0; j < 2; ++j) {
                        bf16x8 bfrag = (chunk == 0) ? b0[kpos * 2 + j] : b1[kpos * 2 + j];
                        acc[f][j] = __builtin_amdgcn_mfma_f32_16x16x32_bf16(
                            afrag, bfrag, acc[f][j], 0, 0, 0);
                    }
                }
            }
        }
    };

    // ---- prologue ----
    stage_x(bk * 8, 0);         // 3 vm-ops/wave (B loads are older, drained by first VMCNT)

    float bv[2];
    #pragma unroll
    for (int j = 0; j < 2; ++j) bv[j] = bias[coh * 32 + j * 16 + l15];

    for (int it = 0; it < 8; ++it) {
        const int u  = bk * 8 + it;
        const int b  = u >> 8;
        const int tile = u & 255;
        const int tw = (tile & 7) * 32;
        const int th = (tile >> 3) * 8;

        #pragma unroll
        for (int f = 0; f < 4; ++f)
            #pragma unroll
            for (int j = 0; j < 2; ++j)
                acc[f][j] = (f32x4){0.f, 0.f, 0.f, 0.f};

        // ---- step A: issue mask (4) + stage chunk1 (3); wait chunk0 ready ----
        const int* mb = mask + (size_t)b * HWSZ;
        int4 mv[2][2];
        #pragma unroll
        for (int fr = 0; fr < 2; ++fr) {
            int h   = th + rg * 2 + fr;
            int wq0 = tw + l4 * 4;
            mv[fr][0] = *(const int4*)(mb + h * 256 + wq0);
            mv[fr][1] = *(const int4*)(mb + h * 256 + wq0 + 16);
        }
        stage_x(u, 1);
        VMCNT(7);               // leaves mask(4)+stage_c1(3): chunk0 + prior stores done
        BARRIER();
        do_mfma(0);
        BARRIER();

        // ---- step B: issue next tile's chunk0 (3); wait chunk1 + mask ready ----
        {
            int un = (u + 1 < 2048) ? (u + 1) : 0;
            stage_x(un, 0);
        }
        VMCNT(3);               // leaves stage_c0(next): chunk1 + mask done
        BARRIER();
        do_mfma(1);
        BARRIER();

        // ---- epilogue: bias + mask, 8 stores/wave ----
        #pragma unroll
        for (int fr = 0; fr < 2; ++fr) {
            int h   = th + rg * 2 + fr;
            int wq0 = tw + l4 * 4;
            float m00 = (float)mv[fr][0].x, m01 = (float)mv[fr][0].y;
            float m02 = (float)mv[fr][0].z, m03 = (float)mv[fr][0].w;
            float m10 = (float)mv[fr][1].x, m11 = (float)mv[fr][1].y;
            float m12 = (float)mv[fr][1].z, m13 = (float)mv[fr][1].w;
            #pragma unroll
            for (int j = 0; j < 2; ++j) {
                int co = coh * 32 + j * 16 + l15;
                float* obase = out + (((size_t)(b * 64 + co)) << 16) + h * 256;
                f32x4 a0 = acc[fr * 2 + 0][j];
                f32x4 a1 = acc[fr * 2 + 1][j];
                float4 o0, o1;
                o0.x = (a0.x + bv[j]) * m00;
                o0.y = (a0.y + bv[j]) * m01;
                o0.z = (a0.z + bv[j]) * m02;
                o0.w = (a0.w + bv[j]) * m03;
                o1.x = (a1.x + bv[j]) * m10;
                o1.y = (a1.y + bv[j]) * m11;
                o1.z = (a1.z + bv[j]) * m12;
                o1.w = (a1.w + bv[j]) * m13;
                *(float4*)(obase + wq0) = o0;
                *(float4*)(obase + wq0 + 16) = o1;
            }
        }
    }
}

extern "C" void kernel_launch(void* const* d_in, const int* in_sizes, int n_in,
                              void* d_out, int out_size, void* d_ws, size_t ws_size,
                              hipStream_t stream) {
    const float* x    = (const float*)d_in[0];
    const int*   mask = (const int*)d_in[1];
    const float* wgt  = (const float*)d_in[2];
    const float* bias = (const float*)d_in[3];
    float* out = (float*)d_out;
    char* ws = (char*)d_ws;     // uses XT_OFF + 64 MiB of ws

    wcvt<<<dim3(144), dim3(256), 0, stream>>>(wgt, ws);
    xcvt<<<dim3(512, 8), dim3(256), 0, stream>>>(x, ws);
    maskconv_mfma<<<dim3(256), dim3(512), 0, stream>>>(ws, mask, bias, out);
}

// Round 21
// 103.237 us; speedup vs baseline: 1.3648x; 1.3648x over previous
//
#include <hip/hip_runtime.h>

typedef __attribute__((ext_vector_type(8))) short bf16x8;
typedef __attribute__((ext_vector_type(4))) float f32x4;

#define HWSZ 65536

__device__ inline unsigned to_bf16u(float f) {
    union { float f; unsigned u; } c; c.f = f;
    unsigned u = c.u;
    return (u + 0x7fffu + ((u >> 16) & 1u)) >> 16;   // round-nearest-even
}

// Weights fp32 [co][ci][9] -> bf16 swizzled wsw [chunk][coh][kpos][co32][4 slot][8]
__global__ void wcvt(const float* __restrict__ wgt, unsigned short* __restrict__ wsw) {
    int idx = blockIdx.x * 256 + threadIdx.x;       // 36864 total
    int co   = idx / 576;
    int rem  = idx - co * 576;
    int ci   = rem / 9;
    int kpos = rem - ci * 9;
    unsigned short v = (unsigned short)to_bf16u(wgt[idx]);
    int coh = co >> 5, col = co & 31;
    int chunk = ci >> 5, cil = ci & 31;
    int slot = (cil >> 3) ^ ((col >> 1) & 3);
    wsw[(((chunk * 2 + coh) * 9 + kpos) * 32 + col) * 32 + slot * 8 + (cil & 7)] = v;
}

__global__ __launch_bounds__(512, 4) void maskconv_mfma(
    const float* __restrict__ x, const int* __restrict__ mask,
    const unsigned short* __restrict__ wsw, const float* __restrict__ bias,
    float* __restrict__ out)
{
    __shared__ unsigned short xs[352 * 32];   // 22528 B: [pixel 10x34 (+pad)][ci32], swizzled
    __shared__ unsigned short wl[36 * 512];   // 36864 B: [coh][kpos][co32][ci32], swizzled (1 chunk)

    const int tid  = threadIdx.x;
    const int lane = tid & 63;
    const int wv   = tid >> 6;          // wave 0..7
    const int wr   = wv & 3;            // row-group: rows wr*2..wr*2+1
    const int coh  = wv >> 2;           // co-half this wave computes
    const int l15  = lane & 15;
    const int l4   = lane >> 4;
    const int oct  = wv & 3;            // ci-octet this wave stages

    // XCD band swizzle: XCD (= bx&7, 256%8==0 so by doesn't shift it) owns a
    // contiguous band of 4 tile-rows -> halo-sharing neighbors are co-XCD-L2.
    const int bx   = blockIdx.x;        // 0..255
    const int tile = ((bx & 7) << 5) | (bx >> 3);
    const int tw = (tile & 7) * 32;
    const int th = (tile >> 3) * 8;
    const int b  = blockIdx.y;

    const float* xb = x + (size_t)b * 64 * HWSZ;
    char* xsb = (char*)xs;
    char* wlb = (char*)wl;

    f32x4 acc[4][2];
    #pragma unroll
    for (int f = 0; f < 4; ++f)
        #pragma unroll
        for (int j = 0; j < 2; ++j)
            acc[f][j] = (f32x4){0.f, 0.f, 0.f, 0.f};

    // ---- stage-task geometry: wave stages octet `oct`, passes p = coh + 2q, q=0..2 ----
    int off[3];
    int dst[3];
    unsigned vmask = 0;   // bit q: pixel in-image (else zeros)
    unsigned wmask = 0;   // bit q: slot exists (pi < 340)
    #pragma unroll
    for (int q = 0; q < 3; ++q) {
        int p  = coh + 2 * q;
        int pi = p * 64 + lane;         // valid < 340
        int r   = pi / 34;
        int lcv = pi - r * 34;
        int gr = th - 1 + r;
        int gc = tw - 1 + lcv;
        unsigned inb = (pi < 340) & ((unsigned)gr < 256u) & ((unsigned)gc < 256u);
        off[q] = inb ? (gr * 256 + gc) : 0;
        vmask |= inb << q;
        wmask |= (unsigned)(pi < 340) << q;
        int s = (lcv >> 1) & 3;
        dst[q] = pi * 64 + ((oct ^ s) << 4);
    }

    // fused stage: fp32 NCHW loads -> bf16 -> swizzled LDS; 3 tasks, 2-deep pipeline
    auto stage_x = [&](int c) {
        const float* srcc = xb + (size_t)(c * 32 + oct * 8) * HWSZ;
        float va[8], vb[8];
        #pragma unroll
        for (int k = 0; k < 8; ++k) va[k] = srcc[(size_t)k * HWSZ + off[0]];
        #pragma unroll
        for (int q = 0; q < 3; ++q) {
            if (q < 2) {                 // prefetch next task
                #pragma unroll
                for (int k = 0; k < 8; ++k) {
                    float t = srcc[(size_t)k * HWSZ + off[q + 1]];
                    if (q == 0) vb[k] = t; else va[k] = t;
                }
            }
            if ((wmask >> q) & 1u) {     // write whenever pixel slot exists (zeros if OOB halo)
                float zf = ((vmask >> q) & 1u) ? 1.f : 0.f;
                unsigned u[4];
                #pragma unroll
                for (int k = 0; k < 4; ++k) {
                    float lo = (q == 1) ? vb[2 * k]     : va[2 * k];
                    float hi = (q == 1) ? vb[2 * k + 1] : va[2 * k + 1];
                    u[k] = to_bf16u(lo * zf) | (to_bf16u(hi * zf) << 16);
                }
                *(uint4*)(xsb + dst[q]) = (uint4){u[0], u[1], u[2], u[3]};
            }
        }
    };

    auto stage_wl = [&](int c) {
        const unsigned short* base = wsw + c * 18432;
        #pragma unroll
        for (int q = 0; q < 5; ++q) {
            int i = wv + 8 * q;
            if (i < 36) {
                const unsigned short* g = base + i * 512 + lane * 8;   // per-lane source
                unsigned short* l = wl + i * 512;
                __builtin_amdgcn_global_load_lds(
                    (const __attribute__((address_space(1))) void*)(const void*)g,
                    (__attribute__((address_space(3))) void*)(void*)l, 16, 0, 0);
            }
        }
    };

    auto do_mfma = [&]() {
        #pragma unroll
        for (int kh = 0; kh < 3; ++kh) {
            #pragma unroll
            for (int kw = 0; kw < 3; ++kw) {
                const int kpos = kh * 3 + kw;
                bf16x8 bfrag[2];
                #pragma unroll
                for (int j = 0; j < 2; ++j) {
                    int col = j * 16 + l15;
                    int sl = l4 ^ ((col >> 1) & 3);
                    bfrag[j] = *(const bf16x8*)(wlb + coh * 18432 + (kpos * 32 + col) * 64 + (sl << 4));
                }
                #pragma unroll
                for (int f = 0; f < 4; ++f) {
                    int lc = (f & 1) * 16 + l15 + kw;
                    int r  = wr * 2 + (f >> 1) + kh;
                    int s  = (lc >> 1) & 3;
                    bf16x8 afrag = *(const bf16x8*)(xsb + (r * 34 + lc) * 64 + ((l4 ^ s) << 4));
                    #pragma unroll
                    for (int j = 0; j < 2; ++j)
                        acc[f][j] = __builtin_amdgcn_mfma_f32_16x16x32_bf16(
                            afrag, bfrag[j], acc[f][j], 0, 0, 0);
                }
            }
        }
    };

    stage_wl(0);
    stage_x(0);
    __syncthreads();            // xs+wl chunk0 ready (drains vmcnt+lgkm)
    do_mfma();
    __syncthreads();            // done reading chunk0
    stage_wl(1);
    stage_x(1);
    __syncthreads();
    do_mfma();

    // ---- epilogue: bias (fp32) + mask, paired float4 stores (full 128B lines) ----
    const int* mb = mask + (size_t)b * HWSZ;
    float bv[2];
    #pragma unroll
    for (int j = 0; j < 2; ++j) bv[j] = bias[coh * 32 + j * 16 + l15];

    #pragma unroll
    for (int rr = 0; rr < 2; ++rr) {
        int h   = th + wr * 2 + rr;
        int wq0 = tw + l4 * 4;
        int4 mv0 = *(const int4*)(mb + h * 256 + wq0);
        int4 mv1 = *(const int4*)(mb + h * 256 + wq0 + 16);
        float m00 = (float)mv0.x, m01 = (float)mv0.y, m02 = (float)mv0.z, m03 = (float)mv0.w;
        float m10 = (float)mv1.x, m11 = (float)mv1.y, m12 = (float)mv1.z, m13 = (float)mv1.w;
        #pragma unroll
        for (int j = 0; j < 2; ++j) {
            int co = coh * 32 + j * 16 + l15;
            float* obase = out + (((size_t)(b * 64 + co)) << 16) + h * 256;
            f32x4 a0 = acc[rr * 2 + 0][j];   // cols wq0..wq0+3
            f32x4 a1 = acc[rr * 2 + 1][j];   // cols wq0+16..+19
            float4 o0, o1;
            o0.x = (a0.x + bv[j]) * m00;
            o0.y = (a0.y + bv[j]) * m01;
            o0.z = (a0.z + bv[j]) * m02;
            o0.w = (a0.w + bv[j]) * m03;
            o1.x = (a1.x + bv[j]) * m10;
            o1.y = (a1.y + bv[j]) * m11;
            o1.z = (a1.z + bv[j]) * m12;
            o1.w = (a1.w + bv[j]) * m13;
            *(float4*)(obase + wq0) = o0;
            *(float4*)(obase + wq0 + 16) = o1;
        }
    }
}

extern "C" void kernel_launch(void* const* d_in, const int* in_sizes, int n_in,
                              void* d_out, int out_size, void* d_ws, size_t ws_size,
                              hipStream_t stream) {
    const float* x    = (const float*)d_in[0];
    const int*   mask = (const int*)d_in[1];
    const float* wgt  = (const float*)d_in[2];
    const float* bias = (const float*)d_in[3];
    float* out = (float*)d_out;
    unsigned short* wsw = (unsigned short*)d_ws;    // 73728 B used

    wcvt<<<dim3(144), dim3(256), 0, stream>>>(wgt, wsw);
    maskconv_mfma<<<dim3(256, 8), dim3(512), 0, stream>>>(x, mask, wsw, bias, out);
}

// Round 22
// 82.727 us; speedup vs baseline: 1.7032x; 1.2479x over previous
//
#include <hip/hip_runtime.h>

typedef __attribute__((ext_vector_type(8))) short bf16x8;
typedef __attribute__((ext_vector_type(4))) float f32x4;

#define HWSZ 65536

__device__ inline unsigned to_bf16u(float f) {
    union { float f; unsigned u; } c; c.f = f;
    unsigned u = c.u;
    return (u + 0x7fffu + ((u >> 16) & 1u)) >> 16;   // round-nearest-even
}

// packed fp32x2 -> bf16x2 (RNE), low word = lo
__device__ inline unsigned cvt_pk_bf16(float lo, float hi) {
    unsigned r;
    asm("v_cvt_pk_bf16_f32 %0, %1, %2" : "=v"(r) : "v"(lo), "v"(hi));
    return r;
}

// Weights fp32 [co][ci][9] -> bf16 swizzled wsw [chunk][coh][kpos][co32][4 slot][8]
__global__ void wcvt(const float* __restrict__ wgt, unsigned short* __restrict__ wsw) {
    int idx = blockIdx.x * 256 + threadIdx.x;       // 36864 total
    int co   = idx / 576;
    int rem  = idx - co * 576;
    int ci   = rem / 9;
    int kpos = rem - ci * 9;
    unsigned short v = (unsigned short)to_bf16u(wgt[idx]);
    int coh = co >> 5, col = co & 31;
    int chunk = ci >> 5, cil = ci & 31;
    int slot = (cil >> 3) ^ ((col >> 1) & 3);
    wsw[(((chunk * 2 + coh) * 9 + kpos) * 32 + col) * 32 + slot * 8 + (cil & 7)] = v;
}

__global__ __launch_bounds__(512, 4) void maskconv_mfma(
    const float* __restrict__ x, const int* __restrict__ mask,
    const unsigned short* __restrict__ wsw, const float* __restrict__ bias,
    float* __restrict__ out)
{
    __shared__ unsigned short xs[352 * 32];   // 22528 B: [pixel 10x34 (+pad)][ci32], swizzled
    __shared__ unsigned short wl[36 * 512];   // 36864 B: [coh][kpos][co32][ci32], swizzled (1 chunk)

    const int tid  = threadIdx.x;
    const int lane = tid & 63;
    const int wv   = tid >> 6;          // wave 0..7
    const int wr   = wv & 3;            // row-group: rows wr*2..wr*2+1
    const int coh  = wv >> 2;           // co-half this wave computes
    const int l15  = lane & 15;
    const int l4   = lane >> 4;
    const int oct  = wv & 3;            // ci-octet this wave stages

    // XCD band swizzle: XCD (= bx&7) owns a contiguous band of 4 tile-rows ->
    // halo-sharing neighbors are co-XCD-L2.  (256 % 8 == 0 so by doesn't shift it)
    const int bx   = blockIdx.x;        // 0..255
    const int tile = ((bx & 7) << 5) | (bx >> 3);
    const int tw = (tile & 7) * 32;
    const int th = (tile >> 3) * 8;
    const int b  = blockIdx.y;

    const float* xb = x + (size_t)b * 64 * HWSZ;
    char* xsb = (char*)xs;
    char* wlb = (char*)wl;

    f32x4 acc[4][2];
    #pragma unroll
    for (int f = 0; f < 4; ++f)
        #pragma unroll
        for (int j = 0; j < 2; ++j)
            acc[f][j] = (f32x4){0.f, 0.f, 0.f, 0.f};

    // ---- stage-task geometry: wave stages octet `oct`, passes p = coh + 2q, q=0..2 ----
    int off[3];
    int dst[3];
    unsigned vmask = 0;   // bit q: pixel in-image (else zeros)
    unsigned wmask = 0;   // bit q: slot exists (pi < 340)
    #pragma unroll
    for (int q = 0; q < 3; ++q) {
        int p  = coh + 2 * q;
        int pi = p * 64 + lane;         // valid < 340
        int r   = pi / 34;
        int lcv = pi - r * 34;
        int gr = th - 1 + r;
        int gc = tw - 1 + lcv;
        unsigned inb = (pi < 340) & ((unsigned)gr < 256u) & ((unsigned)gc < 256u);
        off[q] = inb ? (gr * 256 + gc) : 0;
        vmask |= inb << q;
        wmask |= (unsigned)(pi < 340) << q;
        int s = (lcv >> 1) & 3;
        dst[q] = pi * 64 + ((oct ^ s) << 4);
    }

    // fused stage: fp32 NCHW loads -> v_cvt_pk_bf16_f32 -> swizzled LDS; 2-deep pipeline
    auto stage_x = [&](int c) {
        const float* srcc = xb + (size_t)(c * 32 + oct * 8) * HWSZ;
        float va[8], vb[8];
        #pragma unroll
        for (int k = 0; k < 8; ++k) va[k] = srcc[(size_t)k * HWSZ + off[0]];
        #pragma unroll
        for (int q = 0; q < 3; ++q) {
            if (q < 2) {                 // prefetch next task
                #pragma unroll
                for (int k = 0; k < 8; ++k) {
                    float t = srcc[(size_t)k * HWSZ + off[q + 1]];
                    if (q == 0) vb[k] = t; else va[k] = t;
                }
            }
            if ((wmask >> q) & 1u) {     // write whenever pixel slot exists (zeros if OOB halo)
                unsigned z = ((vmask >> q) & 1u) ? 0xffffffffu : 0u;
                unsigned u[4];
                #pragma unroll
                for (int k = 0; k < 4; ++k) {
                    float lo = (q == 1) ? vb[2 * k]     : va[2 * k];
                    float hi = (q == 1) ? vb[2 * k + 1] : va[2 * k + 1];
                    u[k] = cvt_pk_bf16(lo, hi) & z;
                }
                *(uint4*)(xsb + dst[q]) = (uint4){u[0], u[1], u[2], u[3]};
            }
        }
    };

    auto stage_wl = [&](int c) {
        const unsigned short* base = wsw + c * 18432;
        #pragma unroll
        for (int q = 0; q < 5; ++q) {
            int i = wv + 8 * q;
            if (i < 36) {
                const unsigned short* g = base + i * 512 + lane * 8;   // per-lane source
                unsigned short* l = wl + i * 512;
                __builtin_amdgcn_global_load_lds(
                    (const __attribute__((address_space(1))) void*)(const void*)g,
                    (__attribute__((address_space(3))) void*)(void*)l, 16, 0, 0);
            }
        }
    };

    auto do_mfma = [&]() {
        #pragma unroll
        for (int kh = 0; kh < 3; ++kh) {
            #pragma unroll
            for (int kw = 0; kw < 3; ++kw) {
                const int kpos = kh * 3 + kw;
                bf16x8 bfrag[2];
                #pragma unroll
                for (int j = 0; j < 2; ++j) {
                    int col = j * 16 + l15;
                    int sl = l4 ^ ((col >> 1) & 3);
                    bfrag[j] = *(const bf16x8*)(wlb + coh * 18432 + (kpos * 32 + col) * 64 + (sl << 4));
                }
                #pragma unroll
                for (int f = 0; f < 4; ++f) {
                    int lc = (f & 1) * 16 + l15 + kw;
                    int r  = wr * 2 + (f >> 1) + kh;
                    int s  = (lc >> 1) & 3;
                    bf16x8 afrag = *(const bf16x8*)(xsb + (r * 34 + lc) * 64 + ((l4 ^ s) << 4));
                    #pragma unroll
                    for (int j = 0; j < 2; ++j)
                        acc[f][j] = __builtin_amdgcn_mfma_f32_16x16x32_bf16(
                            afrag, bfrag[j], acc[f][j], 0, 0, 0);
                }
            }
        }
    };

    stage_wl(0);
    stage_x(0);
    __syncthreads();            // xs+wl chunk0 ready (drains vmcnt+lgkm)
    do_mfma();
    __syncthreads();            // done reading chunk0
    stage_wl(1);
    stage_x(1);
    __syncthreads();
    do_mfma();

    // ---- epilogue: bias (fp32) + mask, paired float4 stores (full 128B lines) ----
    const int* mb = mask + (size_t)b * HWSZ;
    float bv[2];
    #pragma unroll
    for (int j = 0; j < 2; ++j) bv[j] = bias[coh * 32 + j * 16 + l15];

    #pragma unroll
    for (int rr = 0; rr < 2; ++rr) {
        int h   = th + wr * 2 + rr;
        int wq0 = tw + l4 * 4;
        int4 mv0 = *(const int4*)(mb + h * 256 + wq0);
        int4 mv1 = *(const int4*)(mb + h * 256 + wq0 + 16);
        float m00 = (float)mv0.x, m01 = (float)mv0.y, m02 = (float)mv0.z, m03 = (float)mv0.w;
        float m10 = (float)mv1.x, m11 = (float)mv1.y, m12 = (float)mv1.z, m13 = (float)mv1.w;
        #pragma unroll
        for (int j = 0; j < 2; ++j) {
            int co = coh * 32 + j * 16 + l15;
            float* obase = out + (((size_t)(b * 64 + co)) << 16) + h * 256;
            f32x4 a0 = acc[rr * 2 + 0][j];   // cols wq0..wq0+3
            f32x4 a1 = acc[rr * 2 + 1][j];   // cols wq0+16..+19
            float4 o0, o1;
            o0.x = (a0.x + bv[j]) * m00;
            o0.y = (a0.y + bv[j]) * m01;
            o0.z = (a0.z + bv[j]) * m02;
            o0.w = (a0.w + bv[j]) * m03;
            o1.x = (a1.x + bv[j]) * m10;
            o1.y = (a1.y + bv[j]) * m11;
            o1.z = (a1.z + bv[j]) * m12;
            o1.w = (a1.w + bv[j]) * m13;
            *(float4*)(obase + wq0) = o0;
            *(float4*)(obase + wq0 + 16) = o1;
        }
    }
}

extern "C" void kernel_launch(void* const* d_in, const int* in_sizes, int n_in,
                              void* d_out, int out_size, void* d_ws, size_t ws_size,
                              hipStream_t stream) {
    const float* x    = (const float*)d_in[0];
    const int*   mask = (const int*)d_in[1];
    const float* wgt  = (const float*)d_in[2];
    const float* bias = (const float*)d_in[3];
    float* out = (float*)d_out;
    unsigned short* wsw = (unsigned short*)d_ws;    // 73728 B used

    wcvt<<<dim3(144), dim3(256), 0, stream>>>(wgt, wsw);
    maskconv_mfma<<<dim3(256, 8), dim3(512), 0, stream>>>(x, mask, wsw, bias, out);
}